// Round 1
// baseline (10366.264 us; speedup 1.0000x reference)
//
#include <hip/hip_runtime.h>
#include <hip/hip_bf16.h>

// QuaternionLinearAutograd: out_c = x @ hamilton(r,i,j,k slices)  for c=0,1,2
// x: (8192, 4096) fp32.  weights: (1024, 3072) fp32 each.
// Effective B: (4096, 12288). B[qr*1024+k1][c*4096+qc*1024+n1] = sign(qc,qr) * w_{qc^qr}[k1][c*1024+n1]
// Output: 3 x (8192,4096) fp32 concatenated flat: idx = c*8192*4096 + m*4096 + n1.
//
// Strategy: bf16 MFMA GEMM (threshold 8.1e-2 >> bf16 rounding error ~1e-2),
// 128x128 tile / BK=32 / 4 waves / 4x4 16x16x32 frags per wave.
// fp32->bf16 conversion fused into LDS staging (no workspace dependency).
// B^T tile in LDS via in-register 4x4 patch transpose. Sign uniform per tile.

typedef __attribute__((ext_vector_type(4))) float  fx4;
typedef __attribute__((ext_vector_type(8))) short  bfx8;
typedef __attribute__((ext_vector_type(4))) float  accx4;

#define BM 128
#define BN 128
#define BK 32

static __device__ __forceinline__ ushort f2bf(float f) {
  __hip_bfloat16 h = __float2bfloat16(f);
  return *reinterpret_cast<ushort*>(&h);
}

__global__ __launch_bounds__(256) void qlin_kernel(
    const float* __restrict__ x,
    const float* __restrict__ wr_, const float* __restrict__ wi_,
    const float* __restrict__ wj_, const float* __restrict__ wk_,
    float* __restrict__ out)
{
  __shared__ __align__(16) ushort As[BM][BK];  // A tile  [m][k], bf16 bits
  __shared__ __align__(16) ushort Bs[BN][BK];  // B^T tile [n][k], bf16 bits

  const int tid = threadIdx.x;
  const int n0  = blockIdx.x * BN;   // 0..12160
  const int m0  = blockIdx.y * BM;   // 0..8064

  const int gate = n0 >> 12;                 // which of the 3 gate slices
  const int rem  = n0 & 4095;                // col offset inside gate (0..3968)
  const int qc   = rem >> 10;                // quadrant column 0..3
  const int colbase = gate * 1024 + (rem & 1023);  // col into (1024,3072) weight

  // A staging: thread -> (row, k-half). 128 rows x 32 k.
  const int arow = tid >> 1;
  const int acol = (tid & 1) << 4;           // 0 or 16
  const float* aptr = x + (size_t)(m0 + arow) * 4096 + acol;

  // B staging: thread -> 4x4 patch. 32 n-groups x 8 k-groups.
  const int bng = (tid & 31) << 2;           // n offset within tile, 0..124
  const int bkg = (tid >> 5) << 2;           // k offset within tile, 0..28

  // wave / fragment indexing
  const int lane = tid & 63;
  const int wid  = tid >> 6;
  const int wm   = (wid >> 1) * 64;          // wave row origin within tile
  const int wn   = (wid & 1) * 64;           // wave col origin within tile
  const int l15  = lane & 15;
  const int l16  = lane >> 4;

  accx4 acc[4][4];
  #pragma unroll
  for (int i = 0; i < 4; ++i)
    #pragma unroll
    for (int j = 0; j < 4; ++j)
      acc[i][j] = (accx4){0.f, 0.f, 0.f, 0.f};

  fx4 av[4];   // 16 floats of A (one half-row of the tile's k-range)
  fx4 bv[4];   // 4x4 fp32 patch of B (rows = k, cols = n)

  // --- issue global loads for K-step t (128 steps of BK=32) ---
  auto issue_loads = [&](int t) {
    const int qr = t >> 5;                       // quadrant row (1024/32 = 32 steps each)
    const int ci = qc ^ qr;                      // which weight component
    const float* wsel = (ci == 0) ? wr_ : (ci == 1) ? wi_ : (ci == 2) ? wj_ : wk_;
    const float* ap = aptr + t * 32;
    #pragma unroll
    for (int i = 0; i < 4; ++i)
      av[i] = *reinterpret_cast<const fx4*>(ap + i * 4);
    const float* bp = wsel + (size_t)((t & 31) * 32 + bkg) * 3072 + colbase + bng;
    #pragma unroll
    for (int i = 0; i < 4; ++i)
      bv[i] = *reinterpret_cast<const fx4*>(bp + (size_t)i * 3072);
  };

  issue_loads(0);

  for (int t = 0; t < 128; ++t) {
    __syncthreads();   // all waves done reading the previous tile

    // ---- stage: cvt fp32->bf16, write LDS (vmcnt wait auto-inserted) ----
    const int qr = t >> 5;
    const bool neg = (qc == 1 && qr == 2) || (qc == 2 && qr == 3) || (qc == 3 && qr == 1);
    const float sgn = neg ? -1.f : 1.f;

    bfx8 pa0, pa1;
    #pragma unroll
    for (int i = 0; i < 2; ++i) {
      #pragma unroll
      for (int j = 0; j < 4; ++j) {
        pa0[i * 4 + j] = (short)f2bf(av[i][j]);
        pa1[i * 4 + j] = (short)f2bf(av[i + 2][j]);
      }
    }
    *reinterpret_cast<bfx8*>(&As[arow][acol])     = pa0;
    *reinterpret_cast<bfx8*>(&As[arow][acol + 8]) = pa1;

    #pragma unroll
    for (int j = 0; j < 4; ++j) {           // in-register 4x4 transpose
      ushort4 cw;
      cw.x = f2bf(bv[0][j] * sgn);
      cw.y = f2bf(bv[1][j] * sgn);
      cw.z = f2bf(bv[2][j] * sgn);
      cw.w = f2bf(bv[3][j] * sgn);
      *reinterpret_cast<ushort4*>(&Bs[bng + j][bkg]) = cw;
    }

    // issue next tile's loads early: latency hides under this tile's MFMAs
    if (t < 127) issue_loads(t + 1);

    __syncthreads();   // tile ready

    // ---- compute: 8 ds_read_b128 + 16 MFMA ----
    bfx8 af[4], bfr[4];
    #pragma unroll
    for (int f = 0; f < 4; ++f) {
      af[f]  = *reinterpret_cast<const bfx8*>(&As[wm + f * 16 + l15][l16 * 8]);
      bfr[f] = *reinterpret_cast<const bfx8*>(&Bs[wn + f * 16 + l15][l16 * 8]);
    }
    #pragma unroll
    for (int i = 0; i < 4; ++i)
      #pragma unroll
      for (int j = 0; j < 4; ++j)
        acc[i][j] = __builtin_amdgcn_mfma_f32_16x16x32_bf16(af[i], bfr[j], acc[i][j], 0, 0, 0);
  }

  // ---- epilogue: C/D layout col=lane&15, row=(lane>>4)*4+reg (m89-verified) ----
  const size_t gatebase = (size_t)gate * (8192ull * 4096ull);
  #pragma unroll
  for (int i = 0; i < 4; ++i) {
    #pragma unroll
    for (int j = 0; j < 4; ++j) {
      const int ncol = rem + wn + j * 16 + l15;          // col within gate, 0..4095
      #pragma unroll
      for (int r = 0; r < 4; ++r) {
        const int mrow = m0 + wm + i * 16 + (l16 << 2) + r;
        out[gatebase + (size_t)mrow * 4096 + ncol] = acc[i][j][r];
      }
    }
  }
}

extern "C" void kernel_launch(void* const* d_in, const int* in_sizes, int n_in,
                              void* d_out, int out_size, void* d_ws, size_t ws_size,
                              hipStream_t stream) {
  const float* x  = (const float*)d_in[0];
  const float* wr = (const float*)d_in[1];
  const float* wi = (const float*)d_in[2];
  const float* wj = (const float*)d_in[3];
  const float* wk = (const float*)d_in[4];
  // d_in[5] = drop (0) — dropout disabled, bias never added in reference.
  float* out = (float*)d_out;

  dim3 grid(12288 / BN, 8192 / BM);   // 96 x 64 = 6144 blocks
  qlin_kernel<<<grid, 256, 0, stream>>>(x, wr, wi, wj, wk, out);
}

// Round 6
// 1496.803 us; speedup vs baseline: 6.9256x; 6.9256x over previous
//
#include <hip/hip_runtime.h>
#include <hip/hip_bf16.h>

// QuaternionLinearAutograd on MI355X.
// out_c = x @ hamilton(r,i,j,k)[:, gate c]  for c=0,1,2, concatenated flat.
// Effective B[qr*1024+k1][c*4096+qc*1024+n1] = sign(qc,qr) * w_{qc^qr}[k1][c*1024+n1]
//
// Round 6 == round 2 resubmitted (four GPU acquisition timeouts, no data yet).
// Round-1 was scratch-spill-bound (VGPR=56, spill traffic ~25 GB each way).
// Plan: pre-convert operands to bf16 in d_ws (x straight; weights transposed to
// Wt[comp][n:3072][k:1024] so both GEMM operands are K-contiguous), then m97-structure
// 128x128 GEMM with global_load_lds width=16 (no per-thread staging regs at all).
// Quaternion sign applied as uniform XOR of B-fragment sign bits.

typedef __attribute__((ext_vector_type(4))) float        fx4;
typedef __attribute__((ext_vector_type(8))) short        bfx8;
typedef __attribute__((ext_vector_type(4))) float        accx4;
typedef __attribute__((ext_vector_type(4))) unsigned int ux4;

#define WT_ELEMS   (4u * 3072u * 1024u)            // ushorts
#define X_ELEMS    (8192u * 4096u)                 // ushorts
#define WS_NEEDED  ((size_t)(WT_ELEMS + X_ELEMS) * 2u)   // 92,274,688 bytes

static __device__ __forceinline__ ushort f2bf(float f) {
  __hip_bfloat16 h = __float2bfloat16(f);
  return *reinterpret_cast<ushort*>(&h);
}

static __device__ __forceinline__ void gload16(const ushort* g, ushort* l) {
  __builtin_amdgcn_global_load_lds(
      (const __attribute__((address_space(1))) unsigned int*)g,
      (__attribute__((address_space(3))) unsigned int*)l, 16, 0, 0);
}

// ---------------- pass 1a: x fp32 -> bf16 ----------------
__global__ __launch_bounds__(256) void conv_x(const float* __restrict__ x,
                                              ushort* __restrict__ xb) {
  const int total = (int)(X_ELEMS / 8u);           // 4,194,304 chunks of 8
  for (int i = blockIdx.x * 256 + threadIdx.x; i < total; i += gridDim.x * 256) {
    fx4 a = *reinterpret_cast<const fx4*>(x + (size_t)i * 8);
    fx4 b = *reinterpret_cast<const fx4*>(x + (size_t)i * 8 + 4);
    bfx8 o;
    #pragma unroll
    for (int j = 0; j < 4; ++j) {
      o[j]     = (short)f2bf(a[j]);
      o[4 + j] = (short)f2bf(b[j]);
    }
    *reinterpret_cast<bfx8*>(xb + (size_t)i * 8) = o;
  }
}

// ---------------- pass 1b: weights fp32 [1024k][3072n] -> bf16 Wt[comp][3072n][1024k] ----------------
__global__ __launch_bounds__(256) void conv_w(const float* __restrict__ w0,
                                              const float* __restrict__ w1,
                                              const float* __restrict__ w2,
                                              const float* __restrict__ w3,
                                              ushort* __restrict__ wt) {
  __shared__ ushort T[64][65];                     // [k_local][n_local], padded
  const float* w = (blockIdx.z == 0) ? w0 : (blockIdx.z == 1) ? w1
                 : (blockIdx.z == 2) ? w2 : w3;
  ushort* dst = wt + (size_t)blockIdx.z * 3072u * 1024u;
  const int n0 = blockIdx.x * 64;                  // 0..3008
  const int k0 = blockIdx.y * 64;                  // 0..960
  const int tid = threadIdx.x;

  const int rcol = tid & 63, rrow = tid >> 6;      // read 4 rows/iter, coalesced in n
  #pragma unroll
  for (int i = 0; i < 16; ++i) {
    int r = i * 4 + rrow;
    T[r][rcol] = f2bf(w[(size_t)(k0 + r) * 3072 + n0 + rcol]);
  }
  __syncthreads();

  const int wc = (tid & 15) * 4, wr = tid >> 4;    // write 16 rows/iter, 4 k-contig bf16
  #pragma unroll
  for (int i = 0; i < 4; ++i) {
    int r = i * 16 + wr;
    ushort4 v;
    v.x = T[wc + 0][r]; v.y = T[wc + 1][r];
    v.z = T[wc + 2][r]; v.w = T[wc + 3][r];
    *reinterpret_cast<ushort4*>(dst + (size_t)(n0 + r) * 1024 + k0 + wc) = v;
  }
}

// ---------------- pass 2: bf16 GEMM, m97 2-barrier structure ----------------
__global__ __launch_bounds__(256) void qgemm(const ushort* __restrict__ wt,
                                             const ushort* __restrict__ xb,
                                             float* __restrict__ out) {
  __shared__ __align__(16) ushort As[128 * 32];    // [m][k] bf16
  __shared__ __align__(16) ushort Bs[128 * 32];    // [n][k] bf16

  // XCD-bijective swizzle: 6144 = 8 * 768; consecutive in-chunk blocks share the m-panel.
  const int flat = blockIdx.x;
  const int swz  = (flat & 7) * 768 + (flat >> 3);
  const int by = swz / 96, bx = swz % 96;
  const int m0 = by * 128, n0 = bx * 128;

  const int gate = n0 >> 12;
  const int rem  = n0 & 4095;
  const int qc   = rem >> 10;                      // tile never crosses quadrant (1024%128==0)
  const int nb   = gate * 1024 + (rem & 1023);     // row base into Wt[comp]

  const int tid = threadIdx.x, lane = tid & 63, wid = tid >> 6;
  const int wm = (wid >> 1) * 64, wn = (wid & 1) * 64;
  const int l15 = lane & 15, l16 = lane >> 4;

  // staging geometry: per gload round, wave w covers 16 rows (1 KB); 2 rounds per operand
  const int srow = wid * 16 + (lane >> 2);         // row within a 64-row round
  const int scol = (lane & 3) * 8;                 // k-elem offset (16B granule)
  const ushort* aP = xb + (size_t)(m0 + srow) * 4096 + scol;
  const ushort* bP = wt + (size_t)(nb + srow) * 1024 + scol;
  ushort* aL = As + wid * 16 * 32;                 // wave-uniform LDS base
  ushort* bL = Bs + wid * 16 * 32;

  accx4 acc[4][4];
  #pragma unroll
  for (int i = 0; i < 4; ++i)
    #pragma unroll
    for (int j = 0; j < 4; ++j)
      acc[i][j] = (accx4){0.f, 0.f, 0.f, 0.f};

  for (int t = 0; t < 128; ++t) {
    const int qr   = t >> 5;
    const int comp = qc ^ qr;
    const int k1   = (t * 32) & 1023;
    const bool neg = (qc == 1 && qr == 2) || (qc == 2 && qr == 3) || (qc == 3 && qr == 1);
    const ushort* aPt = aP + t * 32;
    const ushort* bPt = bP + (size_t)comp * 3072u * 1024u + k1;

    __syncthreads();                               // everyone done reading previous tile
    gload16(aPt,              aL);
    gload16(aPt + 64 * 4096,  aL + 64 * 32);
    gload16(bPt,              bL);
    gload16(bPt + 64 * 1024,  bL + 64 * 32);
    __syncthreads();                               // compiler drains vmcnt before barrier

    bfx8 af[4];
    ux4  bu[4];
    #pragma unroll
    for (int f = 0; f < 4; ++f) {
      af[f] = *reinterpret_cast<const bfx8*>(As + (wm + f * 16 + l15) * 32 + l16 * 8);
      bu[f] = *reinterpret_cast<const ux4*>(Bs + (wn + f * 16 + l15) * 32 + l16 * 8);
    }
    if (neg) {
      #pragma unroll
      for (int f = 0; f < 4; ++f) bu[f] ^= 0x80008000u;   // flip bf16 sign bits
    }
    union { ux4 u; bfx8 h; } bc[4];
    #pragma unroll
    for (int f = 0; f < 4; ++f) bc[f].u = bu[f];

    #pragma unroll
    for (int i = 0; i < 4; ++i)
      #pragma unroll
      for (int j = 0; j < 4; ++j)
        acc[i][j] = __builtin_amdgcn_mfma_f32_16x16x32_bf16(af[i], bc[j].h, acc[i][j], 0, 0, 0);
  }

  // epilogue: C/D layout col=lane&15, row=(lane>>4)*4+reg (m89-verified, passed round 1)
  const size_t gatebase = (size_t)gate * (8192ull * 4096ull);
  #pragma unroll
  for (int i = 0; i < 4; ++i) {
    #pragma unroll
    for (int j = 0; j < 4; ++j) {
      const int ncol = rem + wn + j * 16 + l15;
      #pragma unroll
      for (int r = 0; r < 4; ++r) {
        const int mrow = m0 + wm + i * 16 + (l16 << 2) + r;
        out[gatebase + (size_t)mrow * 4096 + ncol] = acc[i][j][r];
      }
    }
  }
}

// ---------------- fallback (round-1 kernel, known-PASS) for small ws ----------------
__global__ __launch_bounds__(256) void qlin_fallback(
    const float* __restrict__ x,
    const float* __restrict__ wr_, const float* __restrict__ wi_,
    const float* __restrict__ wj_, const float* __restrict__ wk_,
    float* __restrict__ out)
{
  __shared__ __align__(16) ushort As[128][32];
  __shared__ __align__(16) ushort Bs[128][32];
  const int tid = threadIdx.x;
  const int n0  = blockIdx.x * 128;
  const int m0  = blockIdx.y * 128;
  const int gate = n0 >> 12, rem = n0 & 4095, qc = rem >> 10;
  const int colbase = gate * 1024 + (rem & 1023);
  const int arow = tid >> 1, acol = (tid & 1) << 4;
  const float* aptr = x + (size_t)(m0 + arow) * 4096 + acol;
  const int bng = (tid & 31) << 2, bkg = (tid >> 5) << 2;
  const int lane = tid & 63, wid = tid >> 6;
  const int wm = (wid >> 1) * 64, wn = (wid & 1) * 64;
  const int l15 = lane & 15, l16 = lane >> 4;
  accx4 acc[4][4];
  #pragma unroll
  for (int i = 0; i < 4; ++i)
    #pragma unroll
    for (int j = 0; j < 4; ++j) acc[i][j] = (accx4){0.f,0.f,0.f,0.f};

  for (int t = 0; t < 128; ++t) {
    const int qr = t >> 5, ci = qc ^ qr;
    const float* wsel = (ci==0)?wr_:(ci==1)?wi_:(ci==2)?wj_:wk_;
    const bool neg = (qc==1&&qr==2)||(qc==2&&qr==3)||(qc==3&&qr==1);
    const float sgn = neg ? -1.f : 1.f;
    __syncthreads();
    {
      const float* ap = aptr + t * 32;
      fx4 av0 = *reinterpret_cast<const fx4*>(ap);
      fx4 av1 = *reinterpret_cast<const fx4*>(ap + 4);
      fx4 av2 = *reinterpret_cast<const fx4*>(ap + 8);
      fx4 av3 = *reinterpret_cast<const fx4*>(ap + 12);
      bfx8 p0, p1;
      #pragma unroll
      for (int j = 0; j < 4; ++j) {
        p0[j] = (short)f2bf(av0[j]); p0[4+j] = (short)f2bf(av1[j]);
        p1[j] = (short)f2bf(av2[j]); p1[4+j] = (short)f2bf(av3[j]);
      }
      *reinterpret_cast<bfx8*>(&As[arow][acol])     = p0;
      *reinterpret_cast<bfx8*>(&As[arow][acol + 8]) = p1;
      const float* bp = wsel + (size_t)((t & 31) * 32 + bkg) * 3072 + colbase + bng;
      #pragma unroll
      for (int j = 0; j < 4; ++j) {
        fx4 bv = *reinterpret_cast<const fx4*>(bp + (size_t)j * 3072);
        ushort4 cw;
        cw.x = f2bf(bv[0]*sgn); cw.y = f2bf(bv[1]*sgn);
        cw.z = f2bf(bv[2]*sgn); cw.w = f2bf(bv[3]*sgn);
        *reinterpret_cast<ushort4*>(&Bs[bng + j][bkg]) = cw;
      }
    }
    __syncthreads();
    bfx8 af[4], bfr[4];
    #pragma unroll
    for (int f = 0; f < 4; ++f) {
      af[f]  = *reinterpret_cast<const bfx8*>(&As[wm + f*16 + l15][l16*8]);
      bfr[f] = *reinterpret_cast<const bfx8*>(&Bs[wn + f*16 + l15][l16*8]);
    }
    #pragma unroll
    for (int i = 0; i < 4; ++i)
      #pragma unroll
      for (int j = 0; j < 4; ++j)
        acc[i][j] = __builtin_amdgcn_mfma_f32_16x16x32_bf16(af[i], bfr[j], acc[i][j], 0, 0, 0);
  }
  const size_t gatebase = (size_t)gate * (8192ull * 4096ull);
  #pragma unroll
  for (int i = 0; i < 4; ++i)
    #pragma unroll
    for (int j = 0; j < 4; ++j) {
      const int ncol = rem + wn + j * 16 + l15;
      #pragma unroll
      for (int r = 0; r < 4; ++r) {
        const int mrow = m0 + wm + i * 16 + (l16 << 2) + r;
        out[gatebase + (size_t)mrow * 4096 + ncol] = acc[i][j][r];
      }
    }
}

extern "C" void kernel_launch(void* const* d_in, const int* in_sizes, int n_in,
                              void* d_out, int out_size, void* d_ws, size_t ws_size,
                              hipStream_t stream) {
  const float* x  = (const float*)d_in[0];
  const float* wr = (const float*)d_in[1];
  const float* wi = (const float*)d_in[2];
  const float* wj = (const float*)d_in[3];
  const float* wk = (const float*)d_in[4];
  float* out = (float*)d_out;

  if (ws_size >= WS_NEEDED) {
    ushort* wt = (ushort*)d_ws;                    // Wt[4][3072][1024] bf16
    ushort* xb = wt + WT_ELEMS;                    // x bf16 [8192][4096]
    conv_x<<<4096, 256, 0, stream>>>(x, xb);
    dim3 gw(48, 16, 4);
    conv_w<<<gw, 256, 0, stream>>>(wr, wi, wj, wk, wt);
    qgemm<<<6144, 256, 0, stream>>>(wt, xb, out);
  } else {
    dim3 grid(96, 64);
    qlin_fallback<<<grid, 256, 0, stream>>>(x, wr, wi, wj, wk, out);
  }
}

// Round 7
// 1216.633 us; speedup vs baseline: 8.5205x; 1.2303x over previous
//
#include <hip/hip_runtime.h>
#include <hip/hip_bf16.h>

// QuaternionLinearAutograd on MI355X.
// out_c = x @ hamilton(r,i,j,k)[:, gate c]  for c=0,1,2, concatenated flat.
// Effective B[qr*1024+k1][c*4096+qc*1024+n1] = sign(qc,qr) * w_{qc^qr}[k1][c*1024+n1]
//
// Round 7: round-6 confirmed spill fix (778 TF, MfmaUtil 35% = m97 ceiling).
// Now: T3+T4 deep pipeline. 256x256 tile, BK=32, 8 waves (2Mx4N), ring-4 LDS
// (4 x 32KB = 128KB), counted vmcnt(8) across raw s_barrier (never drain 0 in
// main loop), T2 granule-rotation swizzle (both-sides: pre-permuted global src
// + swizzled ds_read), T5 setprio around MFMA cluster.

typedef __attribute__((ext_vector_type(4))) float        fx4;
typedef __attribute__((ext_vector_type(8))) short        bfx8;
typedef __attribute__((ext_vector_type(4))) float        accx4;
typedef __attribute__((ext_vector_type(4))) unsigned int ux4;

#define WT_ELEMS   (4u * 3072u * 1024u)            // ushorts
#define X_ELEMS    (8192u * 4096u)                 // ushorts
#define WS_NEEDED  ((size_t)(WT_ELEMS + X_ELEMS) * 2u)   // 92,274,688 bytes

static __device__ __forceinline__ ushort f2bf(float f) {
  __hip_bfloat16 h = __float2bfloat16(f);
  return *reinterpret_cast<ushort*>(&h);
}

static __device__ __forceinline__ void gload16(const ushort* g, ushort* l) {
  __builtin_amdgcn_global_load_lds(
      (const __attribute__((address_space(1))) unsigned int*)g,
      (__attribute__((address_space(3))) unsigned int*)l, 16, 0, 0);
}

// ---------------- pass 1a: x fp32 -> bf16 ----------------
__global__ __launch_bounds__(256) void conv_x(const float* __restrict__ x,
                                              ushort* __restrict__ xb) {
  const int total = (int)(X_ELEMS / 8u);
  for (int i = blockIdx.x * 256 + threadIdx.x; i < total; i += gridDim.x * 256) {
    fx4 a = *reinterpret_cast<const fx4*>(x + (size_t)i * 8);
    fx4 b = *reinterpret_cast<const fx4*>(x + (size_t)i * 8 + 4);
    bfx8 o;
    #pragma unroll
    for (int j = 0; j < 4; ++j) {
      o[j]     = (short)f2bf(a[j]);
      o[4 + j] = (short)f2bf(b[j]);
    }
    *reinterpret_cast<bfx8*>(xb + (size_t)i * 8) = o;
  }
}

// ---------------- pass 1b: weights fp32 [1024k][3072n] -> bf16 Wt[comp][3072n][1024k] ----------------
__global__ __launch_bounds__(256) void conv_w(const float* __restrict__ w0,
                                              const float* __restrict__ w1,
                                              const float* __restrict__ w2,
                                              const float* __restrict__ w3,
                                              ushort* __restrict__ wt) {
  __shared__ ushort T[64][65];
  const float* w = (blockIdx.z == 0) ? w0 : (blockIdx.z == 1) ? w1
                 : (blockIdx.z == 2) ? w2 : w3;
  ushort* dst = wt + (size_t)blockIdx.z * 3072u * 1024u;
  const int n0 = blockIdx.x * 64;
  const int k0 = blockIdx.y * 64;
  const int tid = threadIdx.x;

  const int rcol = tid & 63, rrow = tid >> 6;
  #pragma unroll
  for (int i = 0; i < 16; ++i) {
    int r = i * 4 + rrow;
    T[r][rcol] = f2bf(w[(size_t)(k0 + r) * 3072 + n0 + rcol]);
  }
  __syncthreads();

  const int wc = (tid & 15) * 4, wr = tid >> 4;
  #pragma unroll
  for (int i = 0; i < 4; ++i) {
    int r = i * 16 + wr;
    ushort4 v;
    v.x = T[wc + 0][r]; v.y = T[wc + 1][r];
    v.z = T[wc + 2][r]; v.w = T[wc + 3][r];
    *reinterpret_cast<ushort4*>(dst + (size_t)(n0 + r) * 1024 + k0 + wc) = v;
  }
}

// ---------------- pass 2: 256^2 ring-4 counted-vmcnt bf16 GEMM ----------------
// LDS buffer (per kt&3): A[256 rows][4 slots of 8 bf16] then B same. 32KB/buf.
// Swizzle: data granule c of row r lives at slot (c + (r>>1)) & 3.
// Staged via linear global_load_lds with inverse-permuted global source.
__global__ __launch_bounds__(512, 2) void qgemm(const ushort* __restrict__ wt,
                                                const ushort* __restrict__ xb,
                                                float* __restrict__ out) {
  __shared__ __align__(16) ushort lds[65536];    // 4 x (A 8192 + B 8192) ushorts

  // XCD-bijective swizzle: 1536 = 8 * 192
  const int flat = blockIdx.x;
  const int swzb = (flat & 7) * 192 + (flat >> 3);
  const int by = swzb / 48, bx = swzb % 48;
  const int m0 = by * 256, n0 = bx * 256;

  const int gate = n0 >> 12;
  const int rem  = n0 & 4095;                    // 1024%256==0: single quadrant per tile
  const int qc   = rem >> 10;
  const int nb   = gate * 1024 + (rem & 1023);   // row base into Wt[comp]

  const int tid = threadIdx.x, lane = tid & 63, wid = tid >> 6;
  const int wr = wid >> 2, wc = wid & 3;         // 2 x 4 wave grid; per-wave out 128x64
  const int l15 = lane & 15, l16 = lane >> 4;

  // staging: 512 threads; thread covers row (tid>>2) and row+128, one 16B granule each.
  const int srow = tid >> 2;                     // 0..127
  const int sg   = ((tid & 3) - (srow >> 1)) & 3;  // inverse-permuted global granule
  const ushort* aG0 = xb + (size_t)(m0 + srow) * 4096 + sg * 8;
  const ushort* bG0 = wt + (size_t)(nb + srow) * 1024 + sg * 8;
  const int aLo = wid * 512;                     // wave-uniform LDS base (ushorts)
  const int bLo = 8192 + wid * 512;

  accx4 acc[8][4];
  #pragma unroll
  for (int f = 0; f < 8; ++f)
    #pragma unroll
    for (int j = 0; j < 4; ++j)
      acc[f][j] = (accx4){0.f, 0.f, 0.f, 0.f};

  auto stage = [&](int kt) {
    const int buf  = (kt & 3) * 16384;
    const int comp = qc ^ (kt >> 5);             // 1024/32 = 32 K-steps per quadrant row
    const ushort* aS = aG0 + kt * 32;
    const ushort* bS = bG0 + (size_t)comp * 3145728u + ((kt * 32) & 1023);
    gload16(aS,              lds + buf + aLo);
    gload16(aS + 128 * 4096, lds + buf + aLo + 4096);
    gload16(bS,              lds + buf + bLo);
    gload16(bS + 128 * 1024, lds + buf + bLo + 4096);
  };

  // prologue: 3 K-tiles in flight; oldest must land before first read.
  stage(0); stage(1); stage(2);
  asm volatile("s_waitcnt vmcnt(8)" ::: "memory");
  __builtin_amdgcn_sched_barrier(0);
  __builtin_amdgcn_s_barrier();
  __builtin_amdgcn_sched_barrier(0);

  for (int t = 0; t < 128; ++t) {
    const int buf = (t & 3) * 16384;
    const int qr  = t >> 5;
    const bool neg = (qc == 1 && qr == 2) || (qc == 2 && qr == 3) || (qc == 3 && qr == 1);

    bfx8 af[8];
    ux4  bu[4];
    #pragma unroll
    for (int f = 0; f < 8; ++f) {
      const int row  = wr * 128 + f * 16 + l15;
      const int slot = (l16 + (row >> 1)) & 3;
      af[f] = *reinterpret_cast<const bfx8*>(lds + buf + row * 32 + slot * 8);
    }
    #pragma unroll
    for (int j = 0; j < 4; ++j) {
      const int row  = wc * 64 + j * 16 + l15;
      const int slot = (l16 + (row >> 1)) & 3;
      bu[j] = *reinterpret_cast<const ux4*>(lds + buf + 8192 + row * 32 + slot * 8);
    }
    if (neg) {
      #pragma unroll
      for (int j = 0; j < 4; ++j) bu[j] ^= 0x80008000u;   // flip bf16 sign bits
    }
    union { ux4 u; bfx8 h; } bc[4];
    #pragma unroll
    for (int j = 0; j < 4; ++j) bc[j].u = bu[j];

    if (t < 125) stage(t + 3);                   // ring-4: targets buffer read at t-1

    __builtin_amdgcn_s_setprio(1);
    #pragma unroll
    for (int f = 0; f < 8; ++f)
      #pragma unroll
      for (int j = 0; j < 4; ++j)
        acc[f][j] = __builtin_amdgcn_mfma_f32_16x16x32_bf16(af[f], bc[j].h, acc[f][j], 0, 0, 0);
    __builtin_amdgcn_s_setprio(0);

    // counted drain: ensure K-tile t+1's 4 loads landed; keep the rest in flight.
    if (t < 125)       { asm volatile("s_waitcnt vmcnt(8)" ::: "memory"); }
    else if (t == 125) { asm volatile("s_waitcnt vmcnt(4)" ::: "memory"); }
    else if (t == 126) { asm volatile("s_waitcnt vmcnt(0)" ::: "memory"); }
    if (t < 127) {
      __builtin_amdgcn_sched_barrier(0);
      __builtin_amdgcn_s_barrier();
      __builtin_amdgcn_sched_barrier(0);
    }
  }

  // epilogue: C/D layout col=lane&15, row=(lane>>4)*4+reg (verified rounds 1/6)
  const size_t gatebase = (size_t)gate * (8192ull * 4096ull);
  #pragma unroll
  for (int f = 0; f < 8; ++f) {
    #pragma unroll
    for (int j = 0; j < 4; ++j) {
      const int ncol = rem + wc * 64 + j * 16 + l15;
      #pragma unroll
      for (int r = 0; r < 4; ++r) {
        const int mrow = m0 + wr * 128 + f * 16 + (l16 << 2) + r;
        out[gatebase + (size_t)mrow * 4096 + ncol] = acc[f][j][r];
      }
    }
  }
}

// ---------------- fallback (round-1 kernel, known-PASS) for small ws ----------------
__global__ __launch_bounds__(256) void qlin_fallback(
    const float* __restrict__ x,
    const float* __restrict__ wr_, const float* __restrict__ wi_,
    const float* __restrict__ wj_, const float* __restrict__ wk_,
    float* __restrict__ out)
{
  __shared__ __align__(16) ushort As[128][32];
  __shared__ __align__(16) ushort Bs[128][32];
  const int tid = threadIdx.x;
  const int n0  = blockIdx.x * 128;
  const int m0  = blockIdx.y * 128;
  const int gate = n0 >> 12, rem = n0 & 4095, qc = rem >> 10;
  const int colbase = gate * 1024 + (rem & 1023);
  const int arow = tid >> 1, acol = (tid & 1) << 4;
  const float* aptr = x + (size_t)(m0 + arow) * 4096 + acol;
  const int bng = (tid & 31) << 2, bkg = (tid >> 5) << 2;
  const int lane = tid & 63, wid = tid >> 6;
  const int wm = (wid >> 1) * 64, wn = (wid & 1) * 64;
  const int l15 = lane & 15, l16 = lane >> 4;
  accx4 acc[4][4];
  #pragma unroll
  for (int i = 0; i < 4; ++i)
    #pragma unroll
    for (int j = 0; j < 4; ++j) acc[i][j] = (accx4){0.f,0.f,0.f,0.f};

  for (int t = 0; t < 128; ++t) {
    const int qr = t >> 5, ci = qc ^ qr;
    const float* wsel = (ci==0)?wr_:(ci==1)?wi_:(ci==2)?wj_:wk_;
    const bool neg = (qc==1&&qr==2)||(qc==2&&qr==3)||(qc==3&&qr==1);
    const float sgn = neg ? -1.f : 1.f;
    __syncthreads();
    {
      const float* ap = aptr + t * 32;
      fx4 av0 = *reinterpret_cast<const fx4*>(ap);
      fx4 av1 = *reinterpret_cast<const fx4*>(ap + 4);
      fx4 av2 = *reinterpret_cast<const fx4*>(ap + 8);
      fx4 av3 = *reinterpret_cast<const fx4*>(ap + 12);
      bfx8 p0, p1;
      #pragma unroll
      for (int j = 0; j < 4; ++j) {
        p0[j] = (short)f2bf(av0[j]); p0[4+j] = (short)f2bf(av1[j]);
        p1[j] = (short)f2bf(av2[j]); p1[4+j] = (short)f2bf(av3[j]);
      }
      *reinterpret_cast<bfx8*>(&As[arow][acol])     = p0;
      *reinterpret_cast<bfx8*>(&As[arow][acol + 8]) = p1;
      const float* bp = wsel + (size_t)((t & 31) * 32 + bkg) * 3072 + colbase + bng;
      #pragma unroll
      for (int j = 0; j < 4; ++j) {
        fx4 bv = *reinterpret_cast<const fx4*>(bp + (size_t)j * 3072);
        ushort4 cw;
        cw.x = f2bf(bv[0]*sgn); cw.y = f2bf(bv[1]*sgn);
        cw.z = f2bf(bv[2]*sgn); cw.w = f2bf(bv[3]*sgn);
        *reinterpret_cast<ushort4*>(&Bs[bng + j][bkg]) = cw;
      }
    }
    __syncthreads();
    bfx8 af[4], bfr[4];
    #pragma unroll
    for (int f = 0; f < 4; ++f) {
      af[f]  = *reinterpret_cast<const bfx8*>(&As[wm + f*16 + l15][l16*8]);
      bfr[f] = *reinterpret_cast<const bfx8*>(&Bs[wn + f*16 + l15][l16*8]);
    }
    #pragma unroll
    for (int i = 0; i < 4; ++i)
      #pragma unroll
      for (int j = 0; j < 4; ++j)
        acc[i][j] = __builtin_amdgcn_mfma_f32_16x16x32_bf16(af[i], bfr[j], acc[i][j], 0, 0, 0);
  }
  const size_t gatebase = (size_t)gate * (8192ull * 4096ull);
  #pragma unroll
  for (int i = 0; i < 4; ++i)
    #pragma unroll
    for (int j = 0; j < 4; ++j) {
      const int ncol = rem + wn + j * 16 + l15;
      #pragma unroll
      for (int r = 0; r < 4; ++r) {
        const int mrow = m0 + wm + i * 16 + (l16 << 2) + r;
        out[gatebase + (size_t)mrow * 4096 + ncol] = acc[i][j][r];
      }
    }
}

extern "C" void kernel_launch(void* const* d_in, const int* in_sizes, int n_in,
                              void* d_out, int out_size, void* d_ws, size_t ws_size,
                              hipStream_t stream) {
  const float* x  = (const float*)d_in[0];
  const float* wr = (const float*)d_in[1];
  const float* wi = (const float*)d_in[2];
  const float* wj = (const float*)d_in[3];
  const float* wk = (const float*)d_in[4];
  float* out = (float*)d_out;

  if (ws_size >= WS_NEEDED) {
    ushort* wt = (ushort*)d_ws;                    // Wt[4][3072][1024] bf16
    ushort* xb = wt + WT_ELEMS;                    // x bf16 [8192][4096]
    conv_x<<<4096, 256, 0, stream>>>(x, xb);
    dim3 gw(48, 16, 4);
    conv_w<<<gw, 256, 0, stream>>>(wr, wi, wj, wk, wt);
    qgemm<<<1536, 512, 0, stream>>>(wt, xb, out);  // 32 x 48 tiles of 256^2
  } else {
    dim3 grid(96, 64);
    qlin_fallback<<<grid, 256, 0, stream>>>(x, wr, wi, wj, wk, out);
  }
}